// Round 14
// baseline (112.130 us; speedup 1.0000x reference)
//
#include <hip/hip_runtime.h>
#include <hip/hip_bf16.h>
#include <math.h>

typedef float  f32x4 __attribute__((ext_vector_type(4)));
typedef short  s16x8 __attribute__((ext_vector_type(8)));
typedef unsigned int u32x2 __attribute__((ext_vector_type(2)));
typedef unsigned int u32x4 __attribute__((ext_vector_type(4)));

constexpr int kNRays = 16384;
constexpr int kOffDepth   = kNRays * 3;
constexpr int kOffAcc     = kOffDepth + kNRays;
constexpr int kOffWeights = kOffAcc + kNRays;
constexpr int kStride = 3072;   // persistent waves: 768 blocks x 4 waves

// Pre-staged A-fragment regions in d_ws (ushort offsets) -- r7 layout
constexpr int kWg0 = 0;      // 32x64  KT=1 MT=4
constexpr int kWg1 = 2048;   // 64x64  KT=2 MT=4
constexpr int kWd  = 6144;   // 64x16  KT=2 MT=1 (dperm)
constexpr int kWc0 = 7168;   // 24x64  KT=1 MT=4 (bc0 folded at k=24)
constexpr int kWc1 = 9216;
constexpr int kWc2 = 13312;
constexpr int kWch = 17408;  // 64x3   KT=2 MT=1
constexpr int kWsTotal = 18432;

__device__ __forceinline__ ushort f2bf(float x) {
    unsigned u = __float_as_uint(x);
    return (ushort)((u + 0x7FFFu + ((u >> 16) & 1u)) >> 16);
}
__device__ __forceinline__ unsigned pk2(float lo, float hi) {
    __hip_bfloat162 h = __float22bfloat162_rn(float2{lo, hi});
    return *reinterpret_cast<unsigned*>(&h);   // v_cvt_pk_bf16_f32
}
// ReLU on a packed bf16 pair: int16 max with 0 is exact bf16 ReLU (sign bit = int16 sign).
__device__ __forceinline__ unsigned pk2r(float lo, float hi) {
    unsigned p = pk2(lo, hi), r;
    asm("v_pk_max_i16 %0, %1, 0" : "=v"(r) : "v"(p));
    return r;
}
__device__ __forceinline__ float sel4(float v0, float v1, float v2, float v3, int s) {
    float a = (s & 1) ? v1 : v0;
    float b = (s & 1) ? v3 : v2;
    return (s & 2) ? b : a;
}
// DPP helpers -- ctrl/rmask as template params (builtin requires constants)
template<int CTRL, int RMASK>
__device__ __forceinline__ float dpp_mul(float x) {
    int t = __builtin_amdgcn_update_dpp(0x3f800000, __float_as_int(x), CTRL, RMASK, 0xF, false);
    return x * __int_as_float(t);
}
template<int CTRL, int RMASK>
__device__ __forceinline__ float dpp_add(float x) {
    int t = __builtin_amdgcn_update_dpp(0, __float_as_int(x), CTRL, RMASK, 0xF, false);
    return x + __int_as_float(t);
}
__device__ __forceinline__ float dpp_sum64(float v) {
    v = dpp_add<0x111, 0xF>(v);  // row_shr:1
    v = dpp_add<0x112, 0xF>(v);  // row_shr:2
    v = dpp_add<0x114, 0xF>(v);  // row_shr:4
    v = dpp_add<0x118, 0xF>(v);  // row_shr:8
    v = dpp_add<0x142, 0xA>(v);  // row_bcast:15 -> rows 1,3
    v = dpp_add<0x143, 0xC>(v);  // row_bcast:31 -> rows 2,3
    return __int_as_float(__builtin_amdgcn_readlane(__float_as_int(v), 63));
}

__global__ __launch_bounds__(256) void prep_weights(
    const float* __restrict__ Wg0, const float* __restrict__ Wg1,
    const float* __restrict__ Wd,  const float* __restrict__ Wc0,
    const float* __restrict__ Wc1, const float* __restrict__ Wc2,
    const float* __restrict__ Wch, const float* __restrict__ bc0,
    ushort* __restrict__ ws)
{
    const int i = blockIdx.x * 256 + threadIdx.x;
    if (i >= kWsTotal) return;
    const float* W; int FIN, FOUT, KT, base; bool dperm = false, c0bias = false;
    if (i < kWg1)      { W = Wg0; FIN = 32; FOUT = 64; KT = 1; base = kWg0; }
    else if (i < kWd)  { W = Wg1; FIN = 64; FOUT = 64; KT = 2; base = kWg1; }
    else if (i < kWc0) { W = Wd;  FIN = 64; FOUT = 16; KT = 2; base = kWd; dperm = true; }
    else if (i < kWc1) { W = Wc0; FIN = 24; FOUT = 64; KT = 1; base = kWc0; c0bias = true; }
    else if (i < kWc2) { W = Wc1; FIN = 64; FOUT = 64; KT = 2; base = kWc1; }
    else if (i < kWch) { W = Wc2; FIN = 64; FOUT = 64; KT = 2; base = kWc2; }
    else               { W = Wch; FIN = 64; FOUT = 3;  KT = 2; base = kWch; }
    const int r = i - base;
    const int e = r & 7, l = (r >> 3) & 63, t = r >> 9;
    const int kt = t % KT, mt = t / KT;
    const int k = kt * 32 + ((l >> 4) << 3) + e;
    int j = mt * 16 + (l & 15);
    if (dperm) j = (j == 15) ? 0 : j + 1;   // geo[0] -> col 15
    float w = 0.0f;
    if (k < FIN && j < FOUT) w = W[k * FOUT + j];
    if (c0bias && k == 24 && j < FOUT) w = bc0[j];  // bias row (X row 24 := 1.0)
    ws[i] = f2bf(w);
}

// Fused 64-out layer with precomputed LDS addresses; ReLU via v_pk_max_i16.
template<int KT, bool HASBIAS>
__device__ __forceinline__ void layer64(ushort* __restrict__ Xw,
                                        const ushort* __restrict__ Aws,
                                        const float* __restrict__ bias,
                                        const int* rp, const int* wa,
                                        int g, int lane) {
    s16x8 B[KT][4];
#pragma unroll
    for (int kt = 0; kt < KT; ++kt)
#pragma unroll
        for (int nt = 0; nt < 4; ++nt)
            B[kt][nt] = *(const s16x8*)&Xw[rp[kt * 4 + nt]];
#pragma unroll
    for (int mt = 0; mt < 4; ++mt) {
        const s16x8 A0 = *(const s16x8*)&Aws[((mt * KT + 0) * 64 + lane) * 8];
        s16x8 A1;
        if constexpr (KT == 2) A1 = *(const s16x8*)&Aws[((mt * KT + 1) * 64 + lane) * 8];
        f32x4 b;
        if constexpr (HASBIAS) b = *(const f32x4*)(bias + mt * 16 + (lane >> 4) * 4);
        else                   b = (f32x4){ 0.f, 0.f, 0.f, 0.f };
        f32x4 acc[4];
#pragma unroll
        for (int nt = 0; nt < 4; ++nt) {
            acc[nt] = __builtin_amdgcn_mfma_f32_16x16x32_bf16(A0, B[0][nt], b, 0, 0, 0);
            if constexpr (KT == 2)
                acc[nt] = __builtin_amdgcn_mfma_f32_16x16x32_bf16(A1, B[1][nt], acc[nt], 0, 0, 0);
        }
#pragma unroll
        for (int nt = 0; nt < 4; ++nt)
            *(u32x2*)&Xw[wa[mt * 4 + nt]] =
                (u32x2){ pk2r(acc[nt].x, acc[nt].y), pk2r(acc[nt].z, acc[nt].w) };
    }
}

// Small (16-col-out) layer: MT=1, KT=2.
__device__ __forceinline__ void layer16(const ushort* __restrict__ Xw,
                                        const ushort* __restrict__ Aws,
                                        const int* rp, int lane, f32x4 acc[4]) {
    const s16x8 A0 = *(const s16x8*)&Aws[(0 * 64 + lane) * 8];
    const s16x8 A1 = *(const s16x8*)&Aws[(1 * 64 + lane) * 8];
#pragma unroll
    for (int nt = 0; nt < 4; ++nt) {
        const s16x8 B0 = *(const s16x8*)&Xw[rp[0 * 4 + nt]];
        acc[nt] = __builtin_amdgcn_mfma_f32_16x16x32_bf16(A0, B0, acc[nt], 0, 0, 0);
        const s16x8 B1 = *(const s16x8*)&Xw[rp[1 * 4 + nt]];
        acc[nt] = __builtin_amdgcn_mfma_f32_16x16x32_bf16(A1, B1, acc[nt], 0, 0, 0);
    }
}

// Issue the 16 scattered gather loads for one ray (lane (g,c16) pattern).
__device__ __forceinline__ void gather16(const float2* __restrict__ tb,
                                         float ox, float oy, float oz,
                                         float dx, float dy, float dz,
                                         int c16, int g, float2 (*__restrict__ f2r)[4]) {
    const float step = 1.0f / 63.0f;
    const float tc = (float)c16 * step;
#pragma unroll
    for (int nt = 0; nt < 4; ++nt) {
        const float ts = tc + (float)nt * (16.0f / 63.0f);
        const float zs = fmaf(1.4f, ts, 0.1f);
        const float px = fmaf(dx, zs, ox), py = fmaf(dy, zs, oy), pz = fmaf(dz, zs, oz);
#pragma unroll
        for (int j = 0; j < 4; ++j) {
            const int lv = (j < 2) ? (2 * g + j) : (8 + 2 * g + (j - 2));
            const float res = (float)(32 << lv);
            const float rm1 = res - 1.0f;
            const float hf = 0.5f * rm1;
            const float sx = __builtin_amdgcn_fmed3f(fmaf(px, hf, hf), 0.f, rm1);
            const float sy = __builtin_amdgcn_fmed3f(fmaf(py, hf, hf), 0.f, rm1);
            const float sz = __builtin_amdgcn_fmed3f(fmaf(pz, hf, hf), 0.f, rm1);
            const float idxf = fmaf(sx, res * res, fmaf(sy, res, sz));
            const float szm1 = (lv == 0) ? 32767.f : (lv == 1) ? 262143.f : 524287.f;
            const unsigned idx = (unsigned)(int)fminf(idxf, szm1);
            f2r[nt][j] = tb[((unsigned)lv << 19) + idx];
        }
    }
}

__global__ __launch_bounds__(256, 3) void nerf_fused_kernel(
    const float* __restrict__ rays_o, const float* __restrict__ rays_d,
    const float* __restrict__ tables, const ushort* __restrict__ ws,
    const float* __restrict__ bg0, const float* __restrict__ bg1,
    const float* __restrict__ bd,  const float* __restrict__ bc1,
    const float* __restrict__ bc2, const float* __restrict__ bch,
    float* __restrict__ out)
{
    __shared__ __align__(16) ushort Xs[4 * 4096];
    const int tid  = threadIdx.x;
    const int wid  = tid >> 6;
    const int lane = tid & 63;
    const int c16  = lane & 15;
    const int g    = lane >> 4;
    ushort* Xw = Xs + wid * 4096;
    const int wgid = blockIdx.x * 4 + wid;   // 0..3071 persistent waves

    const float step = 1.0f / 63.0f;
    const float z  = 0.1f + 1.4f * ((float)lane * step);
    const float zn = 0.1f + 1.4f * ((float)(lane + 1) * step);

    // LDS addresses (ushort units), reused by every layer & ray
    int rp[8], wa[16];
#pragma unroll
    for (int kt = 0; kt < 2; ++kt)
#pragma unroll
        for (int nt = 0; nt < 4; ++nt)
            rp[kt * 4 + nt] = (nt * 16 + c16) * 64 + 8 * ((kt * 4 + g) ^ (c16 & 7));
#pragma unroll
    for (int mt = 0; mt < 4; ++mt)
#pragma unroll
        for (int nt = 0; nt < 4; ++nt)
            wa[mt * 4 + nt] = (nt * 16 + c16) * 64
                            + 8 * ((2 * mt + (g >> 1)) ^ (c16 & 7)) + 4 * (g & 1);

    // hoisted ray-independent biases
    const float db0 = bd[g * 4 + 1];
    const float db1 = bd[g * 4 + 2];
    const float db2 = bd[g * 4 + 3];
    const float db3 = bd[(g == 3) ? 0 : g * 4 + 4];
    const float cb0 = bch[0], cb1 = bch[1], cb2 = bch[2];

    const float2* __restrict__ tb = (const float2*)tables;

    // ---- software pipeline over rays: gather(i+1) in flight during MLP(i) ----
    int ray = wgid;
    float dx = rays_d[ray * 3 + 0], dy = rays_d[ray * 3 + 1], dz = rays_d[ray * 3 + 2];
    float2 f2r[4][4];
    {
        const float ox = rays_o[ray * 3 + 0], oy = rays_o[ray * 3 + 1], oz = rays_o[ray * 3 + 2];
        gather16(tb, ox, oy, oz, dx, dy, dz, c16, g, f2r);
    }
    while (true) {
        const int   cray = ray;
        const float cdx = dx, cdy = dy, cdz = dz;

        // pack B0 (first consumption of the in-flight gathers)
        s16x8 B0f[4];
#pragma unroll
        for (int nt = 0; nt < 4; ++nt) {
            u32x4 val = { pk2(f2r[nt][0].x, f2r[nt][0].y),
                          pk2(f2r[nt][1].x, f2r[nt][1].y),
                          pk2(f2r[nt][2].x, f2r[nt][2].y),
                          pk2(f2r[nt][3].x, f2r[nt][3].y) };
            B0f[nt] = *(const s16x8*)&val;
        }

        // issue next ray's gathers (overlaps the MLP below)
        ray += kStride;
        const bool more = (ray < kNRays);
        if (more) {
            const float nox = rays_o[ray * 3 + 0], noy = rays_o[ray * 3 + 1],
                        noz = rays_o[ray * 3 + 2];
            dx = rays_d[ray * 3 + 0]; dy = rays_d[ray * 3 + 1]; dz = rays_d[ray * 3 + 2];
            gather16(tb, nox, noy, noz, dx, dy, dz, c16, g, f2r);
        }

        // ---- g0: 32 -> 64, relu ----
#pragma unroll
        for (int mt = 0; mt < 4; ++mt) {
            const s16x8 A0 = *(const s16x8*)&ws[kWg0 + (mt * 64 + lane) * 8];
            const f32x4 b = *(const f32x4*)(bg0 + mt * 16 + g * 4);
            f32x4 acc[4];
#pragma unroll
            for (int nt = 0; nt < 4; ++nt)
                acc[nt] = __builtin_amdgcn_mfma_f32_16x16x32_bf16(A0, B0f[nt], b, 0, 0, 0);
#pragma unroll
            for (int nt = 0; nt < 4; ++nt)
                *(u32x2*)&Xw[wa[mt * 4 + nt]] =
                    (u32x2){ pk2r(acc[nt].x, acc[nt].y), pk2r(acc[nt].z, acc[nt].w) };
        }

        // ---- g1 ----
        layer64<2, true>(Xw, ws + kWg1, bg1, rp, wa, g, lane);

        // ---- d: 64 -> 16 (cols rotated; col15 = geo[0] logit) ----
        f32x4 accd[4];
        {
            const f32x4 b = { db0, db1, db2, db3 };
#pragma unroll
            for (int nt = 0; nt < 4; ++nt) accd[nt] = b;
        }
        layer16(Xw, ws + kWd, rp, lane, accd);
        const float lgit = sel4(__shfl(accd[0].w, 48 + c16, 64),
                                __shfl(accd[1].w, 48 + c16, 64),
                                __shfl(accd[2].w, 48 + c16, 64),
                                __shfl(accd[3].w, 48 + c16, 64), g);
#pragma unroll
        for (int nt = 0; nt < 4; ++nt)
            *(u32x2*)&Xw[wa[nt]] = (u32x2){ pk2(accd[nt].x, accd[nt].y),
                                            pk2(accd[nt].z, accd[nt].w) };
        Xw[lane * 64 + 8 * (1 ^ (lane & 7)) + 7] = 0x3F00; // row 15 := bf16(0.5)
        {   // SH rows 16..23
            u32x4 w = { pk2(cdx, cdy), pk2(cdz, cdx * cdy), pk2(cdx * cdz, cdy * cdz),
                        pk2(cdx * cdx - cdy * cdy, 3.f * cdz * cdz - 1.f) };
            *(u32x4*)&Xw[lane * 64 + 8 * (2 ^ (lane & 7))] = w;
        }
        {   // rows 24..31 := {1,0,...,0} (feeds folded bc0)
            u32x4 w = { 0x00003F80u, 0u, 0u, 0u };
            *(u32x4*)&Xw[lane * 64 + 8 * (3 ^ (lane & 7))] = w;
        }

        // ---- color MLP ----
        layer64<1, false>(Xw, ws + kWc0, nullptr, rp, wa, g, lane);
        layer64<2, true >(Xw, ws + kWc1, bc1,     rp, wa, g, lane);
        layer64<2, true >(Xw, ws + kWc2, bc2,     rp, wa, g, lane);

        // ---- ch: 64 -> 3 ----
        f32x4 accc[4];
        {
            const f32x4 b = (g == 0) ? (f32x4){ cb0, cb1, cb2, 0.f }
                                     : (f32x4){ 0.f, 0.f, 0.f, 0.f };
#pragma unroll
            for (int nt = 0; nt < 4; ++nt) accc[nt] = b;
        }
        layer16(Xw, ws + kWch, rp, lane, accc);
        const float lr  = sel4(__shfl(accc[0].x, c16, 64), __shfl(accc[1].x, c16, 64),
                               __shfl(accc[2].x, c16, 64), __shfl(accc[3].x, c16, 64), g);
        const float lgr = sel4(__shfl(accc[0].y, c16, 64), __shfl(accc[1].y, c16, 64),
                               __shfl(accc[2].y, c16, 64), __shfl(accc[3].y, c16, 64), g);
        const float lb  = sel4(__shfl(accc[0].z, c16, 64), __shfl(accc[1].z, c16, 64),
                               __shfl(accc[2].z, c16, 64), __shfl(accc[3].z, c16, 64), g);

        const float cr = 1.f / (1.f + __expf(-lr));
        const float cg = 1.f / (1.f + __expf(-lgr));
        const float cb = 1.f / (1.f + __expf(-lb));
        const float gx = lgit - 1.0f;
        const float density = fmaxf(gx, 0.f) + __logf(1.f + __expf(-fabsf(gx)));

        // ---- volume rendering: DPP scan + DPP reductions ----
        const float dnorm = sqrtf(cdx * cdx + cdy * cdy + cdz * cdz);
        float dist = (lane < 63) ? (zn - z) : 1e10f;
        dist *= dnorm;
        const float alpha = 1.0f - __expf(-density * dist);
        float f = 1.0f - alpha + 1e-10f;
        f = dpp_mul<0x111, 0xF>(f);
        f = dpp_mul<0x112, 0xF>(f);
        f = dpp_mul<0x114, 0xF>(f);
        f = dpp_mul<0x118, 0xF>(f);
        f = dpp_mul<0x142, 0xA>(f);
        f = dpp_mul<0x143, 0xC>(f);
        float T = __shfl_up(f, 1, 64);
        if (lane == 0) T = 1.0f;
        const float w = alpha * T;

        out[kOffWeights + cray * 64 + lane] = w;
        const float sr = dpp_sum64(w * cr);
        const float sg = dpp_sum64(w * cg);
        const float sb = dpp_sum64(w * cb);
        const float sd = dpp_sum64(w * z);
        const float sa = dpp_sum64(w);
        if (lane == 0) {
            out[cray * 3 + 0] = sr;
            out[cray * 3 + 1] = sg;
            out[cray * 3 + 2] = sb;
            out[kOffDepth + cray] = sd;
            out[kOffAcc + cray]   = sa;
        }
        if (!more) break;
    }
}

extern "C" void kernel_launch(void* const* d_in, const int* in_sizes, int n_in,
                              void* d_out, int out_size, void* d_ws, size_t ws_size,
                              hipStream_t stream) {
    const float* rays_o = (const float*)d_in[0];
    const float* rays_d = (const float*)d_in[1];
    const float* tables = (const float*)d_in[2];
    const float* Wg0 = (const float*)d_in[3];
    const float* bg0 = (const float*)d_in[4];
    const float* Wg1 = (const float*)d_in[5];
    const float* bg1 = (const float*)d_in[6];
    const float* Wd  = (const float*)d_in[7];
    const float* bd  = (const float*)d_in[8];
    const float* Wc0 = (const float*)d_in[9];
    const float* bc0 = (const float*)d_in[10];
    const float* Wc1 = (const float*)d_in[11];
    const float* bc1 = (const float*)d_in[12];
    const float* Wc2 = (const float*)d_in[13];
    const float* bc2 = (const float*)d_in[14];
    const float* Wch = (const float*)d_in[15];
    const float* bch = (const float*)d_in[16];
    float* out = (float*)d_out;
    ushort* wsp = (ushort*)d_ws;

    prep_weights<<<dim3((kWsTotal + 255) / 256), dim3(256), 0, stream>>>(
        Wg0, Wg1, Wd, Wc0, Wc1, Wc2, Wch, bc0, wsp);

    nerf_fused_kernel<<<dim3(kStride / 4), dim3(256), 0, stream>>>(
        rays_o, rays_d, tables, wsp,
        bg0, bg1, bd, bc1, bc2, bch, out);
}

// Round 15
// 65.563 us; speedup vs baseline: 1.7103x; 1.7103x over previous
//
#include <hip/hip_runtime.h>
#include <hip/hip_bf16.h>
#include <math.h>

typedef float  f32x4 __attribute__((ext_vector_type(4)));
typedef short  s16x8 __attribute__((ext_vector_type(8)));
typedef unsigned int u32x2 __attribute__((ext_vector_type(2)));
typedef unsigned int u32x4 __attribute__((ext_vector_type(4)));

constexpr int kNRays = 16384;
constexpr int kOffDepth   = kNRays * 3;
constexpr int kOffAcc     = kOffDepth + kNRays;
constexpr int kOffWeights = kOffAcc + kNRays;

// Pre-staged A-fragment regions in d_ws (ushort offsets) -- r7 layout
// g0 staged for the REMAPPED gather: level lv = 4j+g at B-slot (g, e=2j+f)
constexpr int kWg0 = 0;      // 32x64  KT=1 MT=4
constexpr int kWg1 = 2048;   // 64x64  KT=2 MT=4
constexpr int kWd  = 6144;   // 64x16  KT=2 MT=1 (dperm)
constexpr int kWc0 = 7168;   // 24x64  KT=1 MT=4 (bc0 folded at k=24)
constexpr int kWc1 = 9216;
constexpr int kWc2 = 13312;
constexpr int kWch = 17408;  // 64x3   KT=2 MT=1
constexpr int kWsTotal = 18432;
// + 16 u32 clamp-constants (pk2 of table[lv][szm1]) at ushort offset kWsTotal
constexpr int kPrepTotal = kWsTotal + 32;

__device__ __forceinline__ ushort f2bf(float x) {
    unsigned u = __float_as_uint(x);
    return (ushort)((u + 0x7FFFu + ((u >> 16) & 1u)) >> 16);
}
__device__ __forceinline__ unsigned pk2(float lo, float hi) {
    __hip_bfloat162 h = __float22bfloat162_rn(float2{lo, hi});
    return *reinterpret_cast<unsigned*>(&h);   // v_cvt_pk_bf16_f32
}
// ReLU on a packed bf16 pair: int16 max with 0 is exact bf16 ReLU.
__device__ __forceinline__ unsigned pk2r(float lo, float hi) {
    unsigned p = pk2(lo, hi), r;
    asm("v_pk_max_i16 %0, %1, 0" : "=v"(r) : "v"(p));
    return r;
}
__device__ __forceinline__ float sel4(float v0, float v1, float v2, float v3, int s) {
    float a = (s & 1) ? v1 : v0;
    float b = (s & 1) ? v3 : v2;
    return (s & 2) ? b : a;
}
// DPP helpers (verified r14)
template<int CTRL, int RMASK>
__device__ __forceinline__ float dpp_mul(float x) {
    int t = __builtin_amdgcn_update_dpp(0x3f800000, __float_as_int(x), CTRL, RMASK, 0xF, false);
    return x * __int_as_float(t);
}
template<int CTRL, int RMASK>
__device__ __forceinline__ float dpp_add(float x) {
    int t = __builtin_amdgcn_update_dpp(0, __float_as_int(x), CTRL, RMASK, 0xF, false);
    return x + __int_as_float(t);
}
__device__ __forceinline__ float dpp_sum64(float v) {
    v = dpp_add<0x111, 0xF>(v);
    v = dpp_add<0x112, 0xF>(v);
    v = dpp_add<0x114, 0xF>(v);
    v = dpp_add<0x118, 0xF>(v);
    v = dpp_add<0x142, 0xA>(v);
    v = dpp_add<0x143, 0xC>(v);
    return __int_as_float(__builtin_amdgcn_readlane(__float_as_int(v), 63));
}

__global__ __launch_bounds__(256) void prep_weights(
    const float* __restrict__ Wg0, const float* __restrict__ Wg1,
    const float* __restrict__ Wd,  const float* __restrict__ Wc0,
    const float* __restrict__ Wc1, const float* __restrict__ Wc2,
    const float* __restrict__ Wch, const float* __restrict__ bc0,
    const float* __restrict__ tables, ushort* __restrict__ ws)
{
    const int i = blockIdx.x * 256 + threadIdx.x;
    if (i >= kPrepTotal) return;
    if (i >= kWsTotal) {
        const int t = i - kWsTotal;
        if (t < 16) {
            const unsigned szm1 = (t == 0) ? 32767u : (t == 1) ? 262143u : 524287u;
            const float2 v = ((const float2*)tables)[((size_t)t << 19) + szm1];
            ((unsigned*)(ws + kWsTotal))[t] = pk2(v.x, v.y);
        }
        return;
    }
    if (i < kWg1) {   // g0: remapped level order (lv = 4j+g at slot e=2j+f)
        const int r = i;
        const int e = r & 7, l = (r >> 3) & 63, mt = r >> 9;
        const int g = (l >> 4) & 3, c = l & 15;
        const int fr = 8 * (e >> 1) + 2 * g + (e & 1);   // feature row = 2*lv + f
        ws[i] = f2bf(Wg0[fr * 64 + 16 * mt + c]);
        return;
    }
    const float* W; int FIN, FOUT, KT, base; bool dperm = false, c0bias = false;
    if (i < kWd)       { W = Wg1; FIN = 64; FOUT = 64; KT = 2; base = kWg1; }
    else if (i < kWc0) { W = Wd;  FIN = 64; FOUT = 16; KT = 2; base = kWd; dperm = true; }
    else if (i < kWc1) { W = Wc0; FIN = 24; FOUT = 64; KT = 1; base = kWc0; c0bias = true; }
    else if (i < kWc2) { W = Wc1; FIN = 64; FOUT = 64; KT = 2; base = kWc1; }
    else if (i < kWch) { W = Wc2; FIN = 64; FOUT = 64; KT = 2; base = kWc2; }
    else               { W = Wch; FIN = 64; FOUT = 3;  KT = 2; base = kWch; }
    const int r = i - base;
    const int e = r & 7, l = (r >> 3) & 63, t = r >> 9;
    const int kt = t % KT, mt = t / KT;
    const int k = kt * 32 + ((l >> 4) << 3) + e;
    int j = mt * 16 + (l & 15);
    if (dperm) j = (j == 15) ? 0 : j + 1;   // geo[0] -> col 15
    float w = 0.0f;
    if (k < FIN && j < FOUT) w = W[k * FOUT + j];
    if (c0bias && k == 24 && j < FOUT) w = bc0[j];  // bias row (X row 24 := 1.0)
    ws[i] = f2bf(w);
}

// Fused 64-out layer with precomputed LDS addresses; ReLU via v_pk_max_i16.
template<int KT, bool HASBIAS>
__device__ __forceinline__ void layer64(ushort* __restrict__ Xw,
                                        const ushort* __restrict__ Aws,
                                        const float* __restrict__ bias,
                                        const int* rp, const int* wa,
                                        int g, int lane) {
    s16x8 B[KT][4];
#pragma unroll
    for (int kt = 0; kt < KT; ++kt)
#pragma unroll
        for (int nt = 0; nt < 4; ++nt)
            B[kt][nt] = *(const s16x8*)&Xw[rp[kt * 4 + nt]];
#pragma unroll
    for (int mt = 0; mt < 4; ++mt) {
        const s16x8 A0 = *(const s16x8*)&Aws[((mt * KT + 0) * 64 + lane) * 8];
        s16x8 A1;
        if constexpr (KT == 2) A1 = *(const s16x8*)&Aws[((mt * KT + 1) * 64 + lane) * 8];
        f32x4 b;
        if constexpr (HASBIAS) b = *(const f32x4*)(bias + mt * 16 + g * 4);
        else                   b = (f32x4){ 0.f, 0.f, 0.f, 0.f };
        f32x4 acc[4];
#pragma unroll
        for (int nt = 0; nt < 4; ++nt) {
            acc[nt] = __builtin_amdgcn_mfma_f32_16x16x32_bf16(A0, B[0][nt], b, 0, 0, 0);
            if constexpr (KT == 2)
                acc[nt] = __builtin_amdgcn_mfma_f32_16x16x32_bf16(A1, B[1][nt], acc[nt], 0, 0, 0);
        }
#pragma unroll
        for (int nt = 0; nt < 4; ++nt)
            *(u32x2*)&Xw[wa[mt * 4 + nt]] =
                (u32x2){ pk2r(acc[nt].x, acc[nt].y), pk2r(acc[nt].z, acc[nt].w) };
    }
}

// Small (16-col-out) layer: MT=1, KT=2.
__device__ __forceinline__ void layer16(const ushort* __restrict__ Xw,
                                        const ushort* __restrict__ Aws,
                                        const int* rp, int lane, f32x4 acc[4]) {
    const s16x8 A0 = *(const s16x8*)&Aws[(0 * 64 + lane) * 8];
    const s16x8 A1 = *(const s16x8*)&Aws[(1 * 64 + lane) * 8];
#pragma unroll
    for (int nt = 0; nt < 4; ++nt) {
        const s16x8 B0 = *(const s16x8*)&Xw[rp[0 * 4 + nt]];
        acc[nt] = __builtin_amdgcn_mfma_f32_16x16x32_bf16(A0, B0, acc[nt], 0, 0, 0);
        const s16x8 B1 = *(const s16x8*)&Xw[rp[1 * 4 + nt]];
        acc[nt] = __builtin_amdgcn_mfma_f32_16x16x32_bf16(A1, B1, acc[nt], 0, 0, 0);
    }
}

__global__ __launch_bounds__(256, 4) void nerf_mfma_kernel(
    const float* __restrict__ rays_o, const float* __restrict__ rays_d,
    const float* __restrict__ tables, const ushort* __restrict__ ws,
    const float* __restrict__ bg0, const float* __restrict__ bg1,
    const float* __restrict__ bd,  const float* __restrict__ bc1,
    const float* __restrict__ bc2, const float* __restrict__ bch,
    float* __restrict__ out)
{
    __shared__ __align__(16) ushort Xs[4 * 4096];
    const int tid  = threadIdx.x;
    const int wid  = tid >> 6;
    const int lane = tid & 63;
    const int c16  = lane & 15;
    const int g    = lane >> 4;
    const int ray  = blockIdx.x * 4 + wid;
    ushort* Xw = Xs + wid * 4096;

    const float ox = rays_o[ray * 3 + 0], oy = rays_o[ray * 3 + 1], oz = rays_o[ray * 3 + 2];
    const float dx = rays_d[ray * 3 + 0], dy = rays_d[ray * 3 + 1], dz = rays_d[ray * 3 + 2];

    const float step = 1.0f / 63.0f;
    const float z  = 0.1f + 1.4f * ((float)lane * step);
    const float zn = 0.1f + 1.4f * ((float)(lane + 1) * step);

    // precomputed LDS addresses (ushort units)
    int rp[8], wa[16];
#pragma unroll
    for (int kt = 0; kt < 2; ++kt)
#pragma unroll
        for (int nt = 0; nt < 4; ++nt)
            rp[kt * 4 + nt] = (nt * 16 + c16) * 64 + 8 * ((kt * 4 + g) ^ (c16 & 7));
#pragma unroll
    for (int mt = 0; mt < 4; ++mt)
#pragma unroll
        for (int nt = 0; nt < 4; ++nt)
            wa[mt * 4 + nt] = (nt * 16 + c16) * 64
                            + 8 * ((2 * mt + (g >> 1)) ^ (c16 & 7)) + 4 * (g & 1);

    // clamp constants for this lane's levels lv = 4j+g (j=1..3)
    const unsigned* cstp = (const unsigned*)(ws + kWsTotal);
    const unsigned cj1 = cstp[4 + g], cj2 = cstp[8 + g], cj3 = cstp[12 + g];

    // ---- hash gather with clamp-skip: lane (g,c16), tile nt, level lv = 4j+g ----
    const float2* __restrict__ tb = (const float2*)tables;
    const float tc = (float)c16 * step;
    s16x8 B0f[4];
#pragma unroll
    for (int nt = 0; nt < 4; ++nt) {
        const float ts = tc + (float)nt * (16.0f / 63.0f);
        const float zs = fmaf(1.4f, ts, 0.1f);
        const float px = fmaf(dx, zs, ox), py = fmaf(dy, zs, oy), pz = fmaf(dz, zs, oz);
        u32x4 val;
        {   // j = 0: lv = g in {0,1,2,3} -- lv0/lv1 never clamp, always load
            const float res = (float)(32 << g);
            const float rm1 = res - 1.0f;
            const float hf = 0.5f * rm1;
            const float sx = __builtin_amdgcn_fmed3f(fmaf(px, hf, hf), 0.f, rm1);
            const float sy = __builtin_amdgcn_fmed3f(fmaf(py, hf, hf), 0.f, rm1);
            const float sz = __builtin_amdgcn_fmed3f(fmaf(pz, hf, hf), 0.f, rm1);
            const float idxf = fmaf(sx, res * res, fmaf(sy, res, sz));
            const float szm1 = (g == 0) ? 32767.f : (g == 1) ? 262143.f : 524287.f;
            const unsigned idx = (unsigned)(int)fminf(idxf, szm1);
            const float2 f2 = tb[((unsigned)g << 19) + idx];
            val[0] = pk2(f2.x, f2.y);
        }
#pragma unroll
        for (int j = 1; j < 4; ++j) {   // lv = 4j+g >= 4: clamp entry 524287
            const int lv = 4 * j + g;
            const float res = (float)(32 << lv);
            const float rm1 = res - 1.0f;
            const float hf = 0.5f * rm1;
            const float sx = __builtin_amdgcn_fmed3f(fmaf(px, hf, hf), 0.f, rm1);
            const float sy = __builtin_amdgcn_fmed3f(fmaf(py, hf, hf), 0.f, rm1);
            const float sz = __builtin_amdgcn_fmed3f(fmaf(pz, hf, hf), 0.f, rm1);
            const float idxf = fmaf(sx, res * res, fmaf(sy, res, sz));
            const int idx = (int)fminf(idxf, 524287.f);
            unsigned u;
            if (__any(idx != 524287)) {
                const float2 f2 = tb[((unsigned)lv << 19) + (unsigned)idx];
                u = pk2(f2.x, f2.y);
            } else {
                u = (j == 1) ? cj1 : (j == 2) ? cj2 : cj3;
            }
            val[j] = u;
        }
        B0f[nt] = *(const s16x8*)&val;
    }

    // ---- g0: 32 -> 64, relu (B direct from gather) ----
#pragma unroll
    for (int mt = 0; mt < 4; ++mt) {
        const s16x8 A0 = *(const s16x8*)&ws[kWg0 + (mt * 64 + lane) * 8];
        const f32x4 b = *(const f32x4*)(bg0 + mt * 16 + g * 4);
        f32x4 acc[4];
#pragma unroll
        for (int nt = 0; nt < 4; ++nt)
            acc[nt] = __builtin_amdgcn_mfma_f32_16x16x32_bf16(A0, B0f[nt], b, 0, 0, 0);
#pragma unroll
        for (int nt = 0; nt < 4; ++nt)
            *(u32x2*)&Xw[wa[mt * 4 + nt]] =
                (u32x2){ pk2r(acc[nt].x, acc[nt].y), pk2r(acc[nt].z, acc[nt].w) };
    }

    // ---- g1: 64 -> 64, relu ----
    layer64<2, true>(Xw, ws + kWg1, bg1, rp, wa, g, lane);

    // ---- d: 64 -> 16 (cols rotated; col15 = geo[0] logit) ----
    f32x4 accd[4];
    {
        const float db0 = bd[g * 4 + 1];
        const float db1 = bd[g * 4 + 2];
        const float db2 = bd[g * 4 + 3];
        const float db3 = bd[(g == 3) ? 0 : g * 4 + 4];
        const f32x4 b = { db0, db1, db2, db3 };
#pragma unroll
        for (int nt = 0; nt < 4; ++nt) accd[nt] = b;
    }
    layer16(Xw, ws + kWd, rp, lane, accd);
    const float lgit = sel4(__shfl(accd[0].w, 48 + c16, 64),
                            __shfl(accd[1].w, 48 + c16, 64),
                            __shfl(accd[2].w, 48 + c16, 64),
                            __shfl(accd[3].w, 48 + c16, 64), g);
#pragma unroll
    for (int nt = 0; nt < 4; ++nt)
        *(u32x2*)&Xw[wa[nt]] = (u32x2){ pk2(accd[nt].x, accd[nt].y),
                                        pk2(accd[nt].z, accd[nt].w) };
    Xw[lane * 64 + 8 * (1 ^ (lane & 7)) + 7] = 0x3F00; // row 15 := bf16(0.5)
    {   // SH rows 16..23 (per-ray uniform)
        u32x4 w = { pk2(dx, dy), pk2(dz, dx * dy), pk2(dx * dz, dy * dz),
                    pk2(dx * dx - dy * dy, 3.f * dz * dz - 1.f) };
        *(u32x4*)&Xw[lane * 64 + 8 * (2 ^ (lane & 7))] = w;
    }
    {   // rows 24..31 := {1,0,...,0}  (row 24 = 1.0 feeds the folded bc0)
        u32x4 w = { 0x00003F80u, 0u, 0u, 0u };
        *(u32x4*)&Xw[lane * 64 + 8 * (3 ^ (lane & 7))] = w;
    }

    // ---- color MLP ----
    layer64<1, false>(Xw, ws + kWc0, nullptr, rp, wa, g, lane);  // bias folded
    layer64<2, true >(Xw, ws + kWc1, bc1,     rp, wa, g, lane);
    layer64<2, true >(Xw, ws + kWc2, bc2,     rp, wa, g, lane);

    // ---- ch: 64 -> 3 ----
    f32x4 accc[4];
    {
        const float cb0 = bch[0], cb1 = bch[1], cb2 = bch[2];
        const f32x4 b = (g == 0) ? (f32x4){ cb0, cb1, cb2, 0.f } : (f32x4){ 0.f, 0.f, 0.f, 0.f };
#pragma unroll
        for (int nt = 0; nt < 4; ++nt) accc[nt] = b;
    }
    layer16(Xw, ws + kWch, rp, lane, accc);
    const float lr  = sel4(__shfl(accc[0].x, c16, 64), __shfl(accc[1].x, c16, 64),
                           __shfl(accc[2].x, c16, 64), __shfl(accc[3].x, c16, 64), g);
    const float lgr = sel4(__shfl(accc[0].y, c16, 64), __shfl(accc[1].y, c16, 64),
                           __shfl(accc[2].y, c16, 64), __shfl(accc[3].y, c16, 64), g);
    const float lb  = sel4(__shfl(accc[0].z, c16, 64), __shfl(accc[1].z, c16, 64),
                           __shfl(accc[2].z, c16, 64), __shfl(accc[3].z, c16, 64), g);

    const float cr = 1.f / (1.f + __expf(-lr));
    const float cg = 1.f / (1.f + __expf(-lgr));
    const float cb = 1.f / (1.f + __expf(-lb));
    const float gx = lgit - 1.0f;
    const float density = fmaxf(gx, 0.f) + __logf(1.f + __expf(-fabsf(gx)));

    // ---- volume rendering: DPP scan + DPP reductions ----
    const float dnorm = sqrtf(dx * dx + dy * dy + dz * dz);
    float dist = (lane < 63) ? (zn - z) : 1e10f;
    dist *= dnorm;
    const float alpha = 1.0f - __expf(-density * dist);
    float f = 1.0f - alpha + 1e-10f;
    f = dpp_mul<0x111, 0xF>(f);
    f = dpp_mul<0x112, 0xF>(f);
    f = dpp_mul<0x114, 0xF>(f);
    f = dpp_mul<0x118, 0xF>(f);
    f = dpp_mul<0x142, 0xA>(f);
    f = dpp_mul<0x143, 0xC>(f);
    float T = __shfl_up(f, 1, 64);
    if (lane == 0) T = 1.0f;
    const float w = alpha * T;

    out[kOffWeights + ray * 64 + lane] = w;
    const float sr = dpp_sum64(w * cr);
    const float sg = dpp_sum64(w * cg);
    const float sb = dpp_sum64(w * cb);
    const float sd = dpp_sum64(w * z);
    const float sa = dpp_sum64(w);
    if (lane == 0) {
        out[ray * 3 + 0] = sr;
        out[ray * 3 + 1] = sg;
        out[ray * 3 + 2] = sb;
        out[kOffDepth + ray] = sd;
        out[kOffAcc + ray]   = sa;
    }
}

extern "C" void kernel_launch(void* const* d_in, const int* in_sizes, int n_in,
                              void* d_out, int out_size, void* d_ws, size_t ws_size,
                              hipStream_t stream) {
    const float* rays_o = (const float*)d_in[0];
    const float* rays_d = (const float*)d_in[1];
    const float* tables = (const float*)d_in[2];
    const float* Wg0 = (const float*)d_in[3];
    const float* bg0 = (const float*)d_in[4];
    const float* Wg1 = (const float*)d_in[5];
    const float* bg1 = (const float*)d_in[6];
    const float* Wd  = (const float*)d_in[7];
    const float* bd  = (const float*)d_in[8];
    const float* Wc0 = (const float*)d_in[9];
    const float* bc0 = (const float*)d_in[10];
    const float* Wc1 = (const float*)d_in[11];
    const float* bc1 = (const float*)d_in[12];
    const float* Wc2 = (const float*)d_in[13];
    const float* bc2 = (const float*)d_in[14];
    const float* Wch = (const float*)d_in[15];
    const float* bch = (const float*)d_in[16];
    float* out = (float*)d_out;
    ushort* wsp = (ushort*)d_ws;

    prep_weights<<<dim3((kPrepTotal + 255) / 256), dim3(256), 0, stream>>>(
        Wg0, Wg1, Wd, Wc0, Wc1, Wc2, Wch, bc0, tables, wsp);

    nerf_mfma_kernel<<<dim3(kNRays / 4), dim3(256), 0, stream>>>(
        rays_o, rays_d, tables, wsp,
        bg0, bg1, bd, bc1, bc2, bch, out);
}